// Round 3
// baseline (7603.567 us; speedup 1.0000x reference)
//
#include <hip/hip_runtime.h>
#include <cstddef>
#include <math.h>

// Problem: B=64, S=1024, F=128, H=512, V=64, T=64. f32 in/out.
// R9 = R8 (batch-partitioned groups) + tagged fire-and-forget exchange:
//  - h element = u64 {u32 packed(hi|lo<<16), u32 step_tag}, ONE relaxed agent
//    atomic store. Tag travels atomically with data -> producer needs NO
//    VMWAIT ack, NO flag store, NO post-cell barrier. Consumer stage-loads
//    poll the data itself (issue loads -> x-part under latency -> check tags
//    -> predicated per-quarter reissue of stale words). Double buffer by step
//    parity keeps the 2-deep overwrite-safety induction. Flags array removed.
//    Cuts the per-step chain from {store-ack, flag-vis, poll-detect, stage}
//    ~4 round trips to {propagate, ~1 retry}.
//  - decoder idx + hf32 exchanges tagged the same way.
//  - STAGE write conflict fix: thread writes words j = col + 16*c2 (was
//    col*4+c2): quarter-wave covers all 8 bank-quads (2 lanes/quad = free).
//    R8's mapping was 8-way (SQ_LDS_BANK_CONFLICT 1.87e8).
//  - 2 barriers/step (was 4).
#define NGROUP 4
#define WPG    32
#define NWG    128
#define BPG    16
#define BB  64
#define HH  512
#define TT  64
#define VV  64
#define FF  128
#define SS  1024

typedef _Float16 f16;
typedef _Float16 f16x8 __attribute__((ext_vector_type(8)));
typedef float    f32x4 __attribute__((ext_vector_type(4)));
typedef unsigned int u32;
typedef u32 u32x4 __attribute__((ext_vector_type(4)));
typedef unsigned long long u64;

#define C1 4.8828125e-4f          // 2^-11
#define C2 2.384185791015625e-7f  // 2^-22

__device__ __forceinline__ void split8(const float* __restrict__ p, f16x8& hi, f16x8& lo) {
  f32x4 u = *(const f32x4*)p;
  f32x4 v = *(const f32x4*)(p + 4);
#pragma unroll
  for (int j = 0; j < 4; ++j) {
    f16 a = (f16)u[j]; hi[j]   = a; lo[j]   = (f16)((u[j] - (float)a) * 2048.0f);
    f16 b = (f16)v[j]; hi[4+j] = b; lo[4+j] = (f16)((v[j] - (float)b) * 2048.0f);
  }
}
__device__ __forceinline__ float sigmf_(float x) { return 1.0f / (1.0f + expf(-x)); }

// far (coherence-point) accessors
__device__ __forceinline__ f32x4 ld16f(const void* p) {
  f32x4 r;
  asm volatile("global_load_dwordx4 %0, %1, off sc0 sc1" : "=v"(r) : "v"(p) : "memory");
  return r;
}
__device__ __forceinline__ void st8f(u64* p, u64 v) {
  __hip_atomic_store(p, v, __ATOMIC_RELAXED, __HIP_MEMORY_SCOPE_AGENT);
}
__device__ __forceinline__ u64 ld8f(const u64* p) {
  return __hip_atomic_load(p, __ATOMIC_RELAXED, __HIP_MEMORY_SCOPE_AGENT);
}
#define VMWAIT asm volatile("s_waitcnt vmcnt(0)" ::: "memory")

#define MFMA(d, a, b) d = __builtin_amdgcn_mfma_f32_16x16x32_f16(a, b, d, 0, 0, 0)

// ---- tagged one-shot h stage ----
// thread (cb=tid>>4 row, ck=tid&15) owns LDS 16B-words j = ck + 16*c2 of row
// cb; word j holds h k-range [8j,8j+8). Source u64 idx = cb*512 + 8j + 2u.
#define STAGE_ISSUE(srcp)                                                     \
  _Pragma("unroll") for (int c2 = 0; c2 < 4; ++c2)                            \
    _Pragma("unroll") for (int u = 0; u < 4; ++u)                             \
      sv[c2*4+u] = ld16f((srcp) + (size_t)cb*512 + (size_t)(ck + 16*c2)*8 + u*2);

// rule #18: tie results through volatile asm + sched_barrier after VMWAIT so
// the register-only tag check can't be hoisted above the wait.
#define STAGE_WAIT(srcp, tg)                                                  \
  for (;;) {                                                                  \
    VMWAIT;                                                                   \
    _Pragma("unroll") for (int u2 = 0; u2 < 16; ++u2)                         \
      asm volatile("" : "+v"(sv[u2]));                                        \
    __builtin_amdgcn_sched_barrier(0);                                        \
    u32 badv[4];                                                              \
    _Pragma("unroll") for (int c2 = 0; c2 < 4; ++c2) {                        \
      badv[c2] = 0;                                                           \
      _Pragma("unroll") for (int u = 0; u < 4; ++u) {                         \
        union { f32x4 f; u32 u4[4]; } U; U.f = sv[c2*4+u];                    \
        badv[c2] |= (U.u4[1] ^ (u32)(tg)) | (U.u4[3] ^ (u32)(tg));            \
      }                                                                       \
    }                                                                         \
    if (__all((badv[0]|badv[1]|badv[2]|badv[3]) == 0)) break;                 \
    __builtin_amdgcn_s_sleep(1);                                              \
    _Pragma("unroll") for (int c2 = 0; c2 < 4; ++c2)                          \
      if (badv[c2]) {                                                         \
        _Pragma("unroll") for (int u = 0; u < 4; ++u)                         \
          sv[c2*4+u] = ld16f((srcp) + (size_t)cb*512 + (size_t)(ck + 16*c2)*8 + u*2); \
      }                                                                       \
  }

// unpack + swizzled LDS write. byte = (cb*1024 + j*16) ^ ((cb&7)<<4);
// quarter-wave (16 lanes, fixed cb) covers all 8 bank-quads (j mod 8 = ck mod 8).
#define STAGE_WRITE()                                                         \
  { const size_t swz = (size_t)((cb & 7) << 4);                               \
    _Pragma("unroll") for (int c2 = 0; c2 < 4; ++c2) {                        \
      u32 hw[4], lw[4];                                                       \
      _Pragma("unroll") for (int u = 0; u < 4; ++u) {                         \
        union { f32x4 f; u32 u4[4]; } U; U.f = sv[c2*4+u];                    \
        hw[u] = (U.u4[0] & 0xffffu) | (U.u4[2] << 16);                        \
        lw[u] = (U.u4[0] >> 16) | (U.u4[2] & 0xffff0000u);                    \
      }                                                                       \
      size_t off = ((size_t)cb*1024 + (size_t)(ck + 16*c2)*16) ^ swz;         \
      *(u32x4*)((char*)sh_hi + off) = (u32x4){hw[0], hw[1], hw[2], hw[3]};    \
      *(u32x4*)((char*)sh_lo + off) = (u32x4){lw[0], lw[1], lw[2], lw[3]};    \
    } }                                                                       \
  __syncthreads();

// A-fragment read (row = batch mn, k-slice s), same swizzle as content layout
#define LDA(s, ah, al)                                                        \
  { size_t o_ = ((size_t)mn * 1024 + (size_t)(s) * 64 + (size_t)(q8 * 2))     \
                ^ (size_t)((mn & 7) << 4);                                    \
    ah = *(const f16x8*)((const char*)sh_hi + o_);                            \
    al = *(const f16x8*)((const char*)sh_lo + o_); }

#define HPART()                                                               \
  _Pragma("unroll") for (int s = 0; s < 16; ++s) {                            \
    f16x8 ah, al; LDA(s, ah, al);                                             \
    MFMA(acc0, ah, whh_h[s]);                                                 \
    MFMA(acc1, al, whh_h[s]);                                                 \
    MFMA(acc1, ah, whh_l[s]);                                                 \
    MFMA(acc2, al, whh_l[s]);                                                 \
  }

// C/D layout: col = lane&15 = h-dim, row = (lane>>4)*4 + r = batch
#define GWRITE()                                                              \
  _Pragma("unroll") for (int r = 0; r < 4; ++r)                               \
    gate_buf[w][q * 4 + r][mn] = acc0[r] + C1 * acc1[r] + C2 * acc2[r];

__global__ void __launch_bounds__(256, 1) lstm_seq2seq(
    const float* __restrict__ sig,   // [B,S,F]
    const int*   __restrict__ tgt,   // [B,T]
    const float* __restrict__ eWih,  // [2048,128]
    const float* __restrict__ eWhh,  // [2048,512]
    const float* __restrict__ eBih,  // [2048]
    const float* __restrict__ eBhh,  // [2048]
    const float* __restrict__ dWih,  // [2048,64]
    const float* __restrict__ dWhh,  // [2048,512]
    const float* __restrict__ dBih,  // [2048]
    const float* __restrict__ dBhh,  // [2048]
    const float* __restrict__ oW,    // [64,512]
    const float* __restrict__ oB,    // [64]
    float*       __restrict__ out,   // [B,T,V]
    unsigned char* __restrict__ ws)
{
  // ws layout (bytes): [0,512) idx64 u64[64] {idx, tag};
  // [4096, 266240) hfg 4 groups x 64KB u64 {f32 h, tag};
  // [266240, 790528) h16 4 groups x 2 bufs x 64KB u64 {packed, tag}.
  // Whole region zeroed every launch (ws re-poisoned 0xAA): zero tag=0 is the
  // "h0 ready" state for h16 buf0; poison tags never equal an expected tag,
  // but zeroing everything keeps it deterministic.
  const int wg = blockIdx.x;
  const int g  = wg >> 5;            // batch group
  const int p  = wg & 31;            // h-dim slice [p*16, p*16+16) per gate
  const int gb = g * BPG;            // global batch base
  u64* idx64  = (u64*)ws;
  u64* hfg    = (u64*)(ws + 4096)   + (size_t)g * 8192;
  u64* h16[2] = { (u64*)(ws + 266240) + (size_t)(g*2 + 0) * 8192,
                  (u64*)(ws + 266240) + (size_t)(g*2 + 1) * 8192 };

  const int tid  = threadIdx.x;
  const int w    = tid >> 6;         // wave = gate (i,f,g,o)
  const int lane = tid & 63;
  const int q    = lane >> 4;
  const int mn   = lane & 15;
  const int q8   = q * 8;
  const int row  = w * HH + p * 16 + mn;  // weight row for this lane's B-frag
  const int cb   = tid >> 4;         // cell/stage: local batch 0..15
  const int ck   = tid & 15;         // cell/stage: dim-slot 0..15
  const int crow = p * 16 + ck;      // cell: h-dim

  __shared__ __attribute__((aligned(16))) f16 sh_hi[16 * 512]; // 16KB swizzled
  __shared__ __attribute__((aligned(16))) f16 sh_lo[16 * 512];
  __shared__ float gate_buf[4][16][17];
  __shared__ float bias_buf[4][16];
  __shared__ __attribute__((aligned(16))) float hrow[512];
  __shared__ double psum[64];

  // ---- weights: W_hh and W_ih hi/lo fragments in registers ----
  f16x8 whh_h[16], whh_l[16], wih_h[4], wih_l[4];
#pragma unroll
  for (int s = 0; s < 16; ++s)
    split8(eWhh + (size_t)row * HH + s * 32 + q8, whh_h[s], whh_l[s]);
#pragma unroll
  for (int s = 0; s < 4; ++s)
    split8(eWih + (size_t)row * FF + s * 32 + q8, wih_h[s], wih_l[s]);
  if (tid < 64) {
    int g4 = tid >> 4, kl = tid & 15;
    int r = g4 * HH + p * 16 + kl;
    bias_buf[g4][kl] = eBih[r] + eBhh[r];
  }
  if (p == 0 && tid < BPG)   // initial idx = target[:,0], tag 1 (fire+forget)
    st8f(idx64 + gb + tid,
         (u64)(u32)tgt[(size_t)(gb + tid) * TT] | (1ull << 32));
  __syncthreads();

  float c_reg = 0.f;
  const f32x4 zero4 = {0.f, 0.f, 0.f, 0.f};

  // ================= encoder: 1024 steps =================
  for (int t = 0; t < SS; ++t) {
    const u64* hsrc = h16[t & 1];
    f32x4 sv[16];
    STAGE_ISSUE(hsrc)                 // h(t) loads in flight under x-part
    f32x4 acc0 = zero4, acc1 = zero4, acc2 = zero4;
    // x-part: h-independent, covers h-store propagation + load latency
    const float* sb = sig + (size_t)(gb + mn) * (SS * FF) + (size_t)t * FF;
#pragma unroll
    for (int s = 0; s < 4; ++s) {
      f16x8 ah, al;
      split8(sb + s * 32 + q8, ah, al);
      MFMA(acc0, ah, wih_h[s]);
      MFMA(acc1, al, wih_h[s]);
      MFMA(acc1, ah, wih_l[s]);
      MFMA(acc2, al, wih_l[s]);
    }
    STAGE_WAIT(hsrc, t)
    STAGE_WRITE()                     // + barrier
    HPART()
    GWRITE()
    __syncthreads();
    // LSTM cell: 1 h-value per thread (f32, precise libm)
    {
      float gi = gate_buf[0][cb][ck] + bias_buf[0][ck];
      float gf = gate_buf[1][cb][ck] + bias_buf[1][ck];
      float gg = gate_buf[2][cb][ck] + bias_buf[2][ck];
      float go = gate_buf[3][cb][ck] + bias_buf[3][ck];
      float c  = sigmf_(gf) * c_reg + sigmf_(gi) * tanhf(gg);
      float h  = sigmf_(go) * tanhf(c);
      c_reg = c;
      f16 hh = (f16)h;
      f16 hl = (f16)((h - (float)hh) * 2048.0f);
      union { f16 h2[2]; u32 u; } pk;
      pk.h2[0] = hh; pk.h2[1] = hl;
      st8f(h16[(t + 1) & 1] + (size_t)cb * HH + crow,
           (u64)pk.u | ((u64)(u32)(t + 1) << 32));   // fire-and-forget
    }
    // no ack, no flag, no barrier — next step's tag check handles visibility
  }

  // ================= decoder setup =================
#pragma unroll
  for (int s = 0; s < 16; ++s)
    split8(dWhh + (size_t)row * HH + s * 32 + q8, whh_h[s], whh_l[s]);
  __syncthreads();
  if (tid < 64) {
    int g4 = tid >> 4, kl = tid & 15;
    int r = g4 * HH + p * 16 + kl;
    bias_buf[g4][kl] = dBih[r] + dBhh[r];
  }
  __syncthreads();

  // ================= decoder: 64 steps =================
  for (int t = 0; t < TT; ++t) {
    // ---- phase A: cell. x = one_hot(idx) -> column gather at cell stage ----
    const u64* hsrc = h16[(SS + t) & 1];
    f32x4 sv[16];
    STAGE_ISSUE(hsrc)
    f32x4 acc0 = zero4, acc1 = zero4, acc2 = zero4;
    STAGE_WAIT(hsrc, SS + t)
    STAGE_WRITE()
    HPART()
    GWRITE()
    __syncthreads();
    {
      u64 iv;                         // poll idx {argmax(t-1) or initial}, tag t+1
      for (;;) {
        iv = ld8f(idx64 + gb + cb);
        if (__all((u32)(iv >> 32) == (u32)(t + 1))) break;
        __builtin_amdgcn_s_sleep(1);
      }
      int ib = (int)(u32)iv;
      float gi = gate_buf[0][cb][ck] + bias_buf[0][ck] + dWih[(size_t)(0*HH + crow) * VV + ib];
      float gf = gate_buf[1][cb][ck] + bias_buf[1][ck] + dWih[(size_t)(1*HH + crow) * VV + ib];
      float gg = gate_buf[2][cb][ck] + bias_buf[2][ck] + dWih[(size_t)(2*HH + crow) * VV + ib];
      float go = gate_buf[3][cb][ck] + bias_buf[3][ck] + dWih[(size_t)(3*HH + crow) * VV + ib];
      float c  = sigmf_(gf) * c_reg + sigmf_(gi) * tanhf(gg);
      float h  = sigmf_(go) * tanhf(c);
      c_reg = c;
      f16 hh = (f16)h;
      f16 hl = (f16)((h - (float)hh) * 2048.0f);
      union { f16 h2[2]; u32 u; } pk;
      pk.h2[0] = hh; pk.h2[1] = hl;
      st8f(h16[(SS + t + 1) & 1] + (size_t)cb * HH + crow,
           (u64)pk.u | ((u64)(u32)(SS + t + 1) << 32));
      st8f(hfg + (size_t)cb * HH + crow,
           (u64)__float_as_uint(h) | ((u64)(u32)(SS + t + 1) << 32));
    }

    // ---- phase B: f64 logits + log_softmax + argmax (WG p<16 = batch p) ----
    if (p < BPG) {
      const u32 tg = (u32)(SS + t + 1);
      if (tid < 128) {                // stage batch p's h row (tagged poll)
        const u64* hp = hfg + (size_t)p * HH + (size_t)tid * 4;
        f32x4 a = ld16f(hp), b2 = ld16f(hp + 2);
        for (;;) {
          VMWAIT;
          asm volatile("" : "+v"(a), "+v"(b2));
          __builtin_amdgcn_sched_barrier(0);
          union { f32x4 f; u32 u4[4]; } A, B2; A.f = a; B2.f = b2;
          u32 bad = (A.u4[1]^tg) | (A.u4[3]^tg) | (B2.u4[1]^tg) | (B2.u4[3]^tg);
          if (__all(bad == 0)) break;
          __builtin_amdgcn_s_sleep(1);
          a = ld16f(hp); b2 = ld16f(hp + 2);
        }
        union { f32x4 f; u32 u4[4]; } A, B2; A.f = a; B2.f = b2;
        hrow[tid*4+0] = __uint_as_float(A.u4[0]);
        hrow[tid*4+1] = __uint_as_float(A.u4[2]);
        hrow[tid*4+2] = __uint_as_float(B2.u4[0]);
        hrow[tid*4+3] = __uint_as_float(B2.u4[2]);
      }
      __syncthreads();
      double acc = 0.0;
      if (w < 2) {                    // waves 0,1 split K=512 in halves
        const float* wr = oW + (size_t)lane * HH + w * 256;
        const float* hr = hrow + w * 256;
#pragma unroll 4
        for (int kc = 0; kc < 64; ++kc) {
          f32x4 hv = *(const f32x4*)(hr + kc * 4);
          f32x4 wv = *(const f32x4*)(wr + kc * 4);
          acc += (double)hv[0]*(double)wv[0] + (double)hv[1]*(double)wv[1]
               + (double)hv[2]*(double)wv[2] + (double)hv[3]*(double)wv[3];
        }
        if (w == 1) psum[lane] = acc;
      }
      __syncthreads();
      if (w == 0) {
        double l = acc + psum[lane] + (double)oB[lane];
        double mx = l; int ai = lane;
#pragma unroll
        for (int o = 32; o > 0; o >>= 1) {
          double om = __shfl_xor(mx, o, 64);
          int    oi = __shfl_xor(ai, o, 64);
          if (om > mx || (om == mx && oi < ai)) { mx = om; ai = oi; }
        }
        double se = exp(l - mx);
#pragma unroll
        for (int o = 32; o > 0; o >>= 1) se += __shfl_xor(se, o, 64);
        double lse = mx + log(se);
        out[((size_t)(gb + p) * TT + t) * VV + lane] = (float)(l - lse);
        if (lane == 0)                // argmax for step t+1, tag t+2
          st8f(idx64 + gb + p, (u64)(u32)ai | ((u64)(u32)(t + 2) << 32));
      }
      __syncthreads();                // protect hrow/psum reuse
    }
  }
}

extern "C" void kernel_launch(void* const* d_in, const int* in_sizes, int n_in,
                              void* d_out, int out_size, void* d_ws, size_t ws_size,
                              hipStream_t stream) {
  (void)in_sizes; (void)n_in; (void)out_size; (void)ws_size;
  // zero: idx64 + hfg + h16 (tags must start != any expected tag; h16 buf0
  // tag 0 + value 0 IS the initial h0 state). ws re-poisoned 0xAA before
  // every timed launch -> must zero every call.
  hipMemsetAsync(d_ws, 0, 790528, stream);
  lstm_seq2seq<<<dim3(NWG), dim3(256), 0, stream>>>(
      (const float*)d_in[0],  (const int*)d_in[1],
      (const float*)d_in[2],  (const float*)d_in[3],
      (const float*)d_in[4],  (const float*)d_in[5],
      (const float*)d_in[6],  (const float*)d_in[7],
      (const float*)d_in[8],  (const float*)d_in[9],
      (const float*)d_in[10], (const float*)d_in[11],
      (float*)d_out, (unsigned char*)d_ws);
}